// Round 1
// baseline (1393.709 us; speedup 1.0000x reference)
//
#include <hip/hip_runtime.h>
#include <hip/hip_bf16.h>

#define BATCH 256
#define TLEN  512
#define HID   256
#define NT    768   // 3*HID threads: thread j owns gate-row j of [3H,H]

typedef _Float16 v2h __attribute__((ext_vector_type(2)));
typedef _Float16 v8h __attribute__((ext_vector_type(8)));

#if defined(__HIP_DEVICE_COMPILE__) && __has_builtin(__builtin_amdgcn_fdot2)
#define FDOT2(a, b, c) __builtin_amdgcn_fdot2((a), (b), (c), false)
#else
static __device__ __host__ __forceinline__ float FDOT2(v2h a, v2h b, float c) {
  return (float)a[0] * (float)b[0] + ((float)a[1] * (float)b[1] + c);
}
#endif

__device__ __forceinline__ float fast_sigmoid(float x) {
  float e = __expf(-x);
  return __builtin_amdgcn_rcpf(1.0f + e);
}
__device__ __forceinline__ float fast_tanh(float x) {
  // |x| <= ~17 here (bounded pre-activations), no overflow risk
  float e = __expf(-2.0f * x);
  return (1.0f - e) * __builtin_amdgcn_rcpf(1.0f + e);
}

__global__ void __launch_bounds__(NT) gru_ae_kernel(
    const float* __restrict__ x,
    const float* __restrict__ w_ih_enc, const float* __restrict__ w_hh_enc,
    const float* __restrict__ b_ih_enc, const float* __restrict__ b_hh_enc,
    const float* __restrict__ w_ih_dec, const float* __restrict__ w_hh_dec,
    const float* __restrict__ b_ih_dec, const float* __restrict__ b_hh_dec,
    const float* __restrict__ w_dense, const float* __restrict__ b_dense,
    float* __restrict__ out)
{
  const int b = blockIdx.x;
  const int j = threadIdx.x;  // 0..767 gate-row index

  __shared__ float h32[HID];                      // fp32 master hidden state
  __shared__ __align__(16) _Float16 h16[HID];     // fp16 copy for dot2 reads
  __shared__ float rbuf[HID];
  __shared__ float zbuf[HID];
  __shared__ float red[HID];                      // dense-layer reduction scratch
  __shared__ float wdl[HID];                      // w_dense row
  __shared__ float xbuf[TLEN];                    // encoder inputs
  __shared__ float obuf[TLEN];                    // decoder outputs
  __shared__ float xcur_s;

  // ---- init ----
  for (int t = j; t < TLEN; t += NT) xbuf[t] = x[(size_t)b * TLEN + t];
  if (j < HID) {
    h32[j] = 0.0f;
    h16[j] = (_Float16)0.0f;
    wdl[j] = w_dense[j];
  }
  const float bd = b_dense[0];

  // ---- load encoder weights: row j of w_hh_enc as 128 packed fp16 pairs ----
  v2h w[HID / 2];
  {
    const float2* wp = (const float2*)w_hh_enc + (size_t)j * (HID / 2);
#pragma unroll
    for (int k = 0; k < HID / 2; ++k) {
      float2 tw = wp[k];
      v2h p; p[0] = (_Float16)tw.x; p[1] = (_Float16)tw.y;
      w[k] = p;
    }
  }
  float wih = w_ih_enc[j];
  float bih = b_ih_enc[j];
  float bhh = b_hh_enc[j];

  __syncthreads();

  // dot(h, w_row): 128 v_dot2_f32_f16, 4 independent accumulator chains
  auto dot_h = [&]() -> float {
    const v8h* hp = (const v8h*)h16;
    float a0 = 0.f, a1 = 0.f, a2 = 0.f, a3 = 0.f;
#pragma unroll
    for (int c = 0; c < HID / 8; ++c) {
      v8h hv = hp[c];
      v2h p0; p0[0] = hv[0]; p0[1] = hv[1];
      v2h p1; p1[0] = hv[2]; p1[1] = hv[3];
      v2h p2; p2[0] = hv[4]; p2[1] = hv[5];
      v2h p3; p3[0] = hv[6]; p3[1] = hv[7];
      a0 = FDOT2(p0, w[4 * c + 0], a0);
      a1 = FDOT2(p1, w[4 * c + 1], a1);
      a2 = FDOT2(p2, w[4 * c + 2], a2);
      a3 = FDOT2(p3, w[4 * c + 3], a3);
    }
    return (a0 + a1) + (a2 + a3);
  };

  // ---- encoder: 512 steps ----
  for (int t = 0; t < TLEN; ++t) {
    float d  = dot_h();
    float xt = xbuf[t];
    float pre = d + bhh;              // h-part incl. b_hh
    float gi  = fmaf(xt, wih, bih);   // i-part incl. b_ih
    if (j < 2 * HID) {
      float v = fast_sigmoid(gi + pre);
      if (j < HID) rbuf[j] = v; else zbuf[j - HID] = v;
    }
    __syncthreads();
    if (j >= 2 * HID) {
      int jj = j - 2 * HID;
      float n    = fast_tanh(fmaf(rbuf[jj], pre, gi));  // tanh(i_n + r*h_n)
      float z    = zbuf[jj];
      float hold = h32[jj];
      float hn   = n + z * (hold - n);                  // (1-z)*n + z*h
      h32[jj] = hn;
      h16[jj] = (_Float16)hn;
    }
    __syncthreads();
  }

  // ---- reload decoder weights ----
  {
    const float2* wp = (const float2*)w_hh_dec + (size_t)j * (HID / 2);
#pragma unroll
    for (int k = 0; k < HID / 2; ++k) {
      float2 tw = wp[k];
      v2h p; p[0] = (_Float16)tw.x; p[1] = (_Float16)tw.y;
      w[k] = p;
    }
  }
  wih = w_ih_dec[j];
  bih = b_ih_dec[j];
  bhh = b_hh_dec[j];

  // ---- x0 = h_n @ w_dense^T + b_dense ----
  if (j < HID) red[j] = h32[j] * wdl[j];
  __syncthreads();
  if (j < 64) {
    float s = (red[j] + red[j + 64]) + (red[j + 128] + red[j + 192]);
    s += __shfl_down(s, 32);
    s += __shfl_down(s, 16);
    s += __shfl_down(s, 8);
    s += __shfl_down(s, 4);
    s += __shfl_down(s, 2);
    s += __shfl_down(s, 1);
    if (j == 0) xcur_s = s + bd;
  }
  __syncthreads();

  // ---- decoder: 512 autoregressive steps ----
  for (int t = 0; t < TLEN; ++t) {
    float d  = dot_h();
    float xt = xcur_s;
    float pre = d + bhh;
    float gi  = fmaf(xt, wih, bih);
    if (j < 2 * HID) {
      float v = fast_sigmoid(gi + pre);
      if (j < HID) rbuf[j] = v; else zbuf[j - HID] = v;
    }
    __syncthreads();
    if (j >= 2 * HID) {
      int jj = j - 2 * HID;
      float n    = fast_tanh(fmaf(rbuf[jj], pre, gi));
      float z    = zbuf[jj];
      float hold = h32[jj];
      float hn   = n + z * (hold - n);
      h32[jj] = hn;
      h16[jj] = (_Float16)hn;
      red[jj] = hn * wdl[jj];         // contribution to next x
    }
    __syncthreads();
    if (j < 64) {
      float s = (red[j] + red[j + 64]) + (red[j + 128] + red[j + 192]);
      s += __shfl_down(s, 32);
      s += __shfl_down(s, 16);
      s += __shfl_down(s, 8);
      s += __shfl_down(s, 4);
      s += __shfl_down(s, 2);
      s += __shfl_down(s, 1);
      if (j == 0) { float xn = s + bd; xcur_s = xn; obuf[t] = xn; }
    }
    __syncthreads();
  }

  // ---- write output with time flip: out[b, t] = xs[T-1-t] ----
  for (int t = j; t < TLEN; t += NT)
    out[(size_t)b * TLEN + t] = obuf[TLEN - 1 - t];
}

extern "C" void kernel_launch(void* const* d_in, const int* in_sizes, int n_in,
                              void* d_out, int out_size, void* d_ws, size_t ws_size,
                              hipStream_t stream) {
  const float* x        = (const float*)d_in[0];
  const float* w_ih_enc = (const float*)d_in[1];
  const float* w_hh_enc = (const float*)d_in[2];
  const float* b_ih_enc = (const float*)d_in[3];
  const float* b_hh_enc = (const float*)d_in[4];
  const float* w_ih_dec = (const float*)d_in[5];
  const float* w_hh_dec = (const float*)d_in[6];
  const float* b_ih_dec = (const float*)d_in[7];
  const float* b_hh_dec = (const float*)d_in[8];
  const float* w_dense  = (const float*)d_in[9];
  const float* b_dense  = (const float*)d_in[10];
  float* out = (float*)d_out;

  hipLaunchKernelGGL(gru_ae_kernel, dim3(BATCH), dim3(NT), 0, stream,
                     x, w_ih_enc, w_hh_enc, b_ih_enc, b_hh_enc,
                     w_ih_dec, w_hh_dec, b_ih_dec, b_hh_dec,
                     w_dense, b_dense, out);
}

// Round 2
// 1173.476 us; speedup vs baseline: 1.1877x; 1.1877x over previous
//
#include <hip/hip_runtime.h>
#include <hip/hip_bf16.h>

#define BATCH 256
#define TLEN  512
#define HID   256
#define NT    512          // thread (jj, half): jj = tid&255 owns hidden unit jj; half = K-split
#define HALF  128          // K elements per thread
#define NCH   16           // 16B LDS chunks per half (128 fp16 / 8)

typedef _Float16 v2h __attribute__((ext_vector_type(2)));
typedef _Float16 v8h __attribute__((ext_vector_type(8)));

#if defined(__HIP_DEVICE_COMPILE__) && __has_builtin(__builtin_amdgcn_fdot2)
#define FDOT2(a, b, c) __builtin_amdgcn_fdot2((a), (b), (c), false)
#else
static __device__ __host__ __forceinline__ float FDOT2(v2h a, v2h b, float c) {
  return (float)a[0] * (float)b[0] + ((float)a[1] * (float)b[1] + c);
}
#endif

__device__ __forceinline__ float fast_sigmoid(float x) {
  float e = __expf(-x);
  return __builtin_amdgcn_rcpf(1.0f + e);
}
__device__ __forceinline__ float fast_tanh(float x) {
  float e = __expf(-2.0f * x);
  return (1.0f - e) * __builtin_amdgcn_rcpf(1.0f + e);
}

__global__ void __launch_bounds__(NT, 2) gru_ae_kernel(
    const float* __restrict__ x,
    const float* __restrict__ w_ih_enc, const float* __restrict__ w_hh_enc,
    const float* __restrict__ b_ih_enc, const float* __restrict__ b_hh_enc,
    const float* __restrict__ w_ih_dec, const float* __restrict__ w_hh_dec,
    const float* __restrict__ b_ih_dec, const float* __restrict__ b_hh_dec,
    const float* __restrict__ w_dense, const float* __restrict__ b_dense,
    float* __restrict__ out)
{
  const int b    = blockIdx.x;
  const int tid  = threadIdx.x;
  const int jj   = tid & (HID - 1);   // hidden unit owned
  const int half = tid >> 8;          // 0 or 1: which K-half

  __shared__ __align__(16) _Float16 h16[HID];   // fp16 h for dot reads
  __shared__ float pr[NT], pz[NT], pn[NT];      // partial dots
  __shared__ float red[HID];                    // dense reduction scratch
  __shared__ float xbuf[TLEN];
  __shared__ float obuf[TLEN];
  __shared__ float xcur_s;

  for (int t = tid; t < TLEN; t += NT) xbuf[t] = x[(size_t)b * TLEN + t];
  if (tid < HID) h16[tid] = (_Float16)0.0f;
  float hreg   = 0.0f;                               // fp32 master h[jj] (tid<HID)
  float wd_reg = (tid < HID) ? w_dense[jj] : 0.0f;
  const float bd = b_dense[0];

  // per-thread weights: rows {jj, H+jj, 2H+jj} of w_hh, cols [half*128, half*128+128)
  v2h wr[HALF / 2], wz[HALF / 2], wn[HALF / 2];
  float wih_r, wih_z, wih_n, bih_r, bih_z, bih_n, bhh_r, bhh_z, bhh_n;

#define LOAD_WEIGHTS(WHH, WIH, BIH, BHH)                                        \
  {                                                                             \
    const float2* r0 = (const float2*)((WHH) + (size_t)(0 * HID + jj) * HID) + half * (HALF / 2); \
    const float2* z0 = (const float2*)((WHH) + (size_t)(1 * HID + jj) * HID) + half * (HALF / 2); \
    const float2* n0 = (const float2*)((WHH) + (size_t)(2 * HID + jj) * HID) + half * (HALF / 2); \
    _Pragma("unroll")                                                           \
    for (int k = 0; k < HALF / 2; ++k) {                                        \
      float2 tr = r0[k]; v2h a; a[0] = (_Float16)tr.x; a[1] = (_Float16)tr.y; wr[k] = a; \
      float2 tz = z0[k]; v2h c; c[0] = (_Float16)tz.x; c[1] = (_Float16)tz.y; wz[k] = c; \
      float2 tn = n0[k]; v2h d; d[0] = (_Float16)tn.x; d[1] = (_Float16)tn.y; wn[k] = d; \
    }                                                                           \
    wih_r = (WIH)[jj]; wih_z = (WIH)[HID + jj]; wih_n = (WIH)[2 * HID + jj];    \
    bih_r = (BIH)[jj]; bih_z = (BIH)[HID + jj]; bih_n = (BIH)[2 * HID + jj];    \
    bhh_r = (BHH)[jj]; bhh_z = (BHH)[HID + jj]; bhh_n = (BHH)[2 * HID + jj];    \
  }

  LOAD_WEIGHTS(w_hh_enc, w_ih_enc, b_ih_enc, b_hh_enc);
  __syncthreads();

  // 3 dots over this thread's K-half: 12 dot2 per 16B LDS read
  auto dots = [&](float& Dr, float& Dz, float& Dn) {
    const v8h* hp = (const v8h*)(h16 + half * HALF);
    float ar0 = 0.f, ar1 = 0.f, az0 = 0.f, az1 = 0.f, an0 = 0.f, an1 = 0.f;
#pragma unroll
    for (int c = 0; c < NCH; ++c) {
      v8h hv = hp[c];
      v2h p0 = __builtin_shufflevector(hv, hv, 0, 1);
      v2h p1 = __builtin_shufflevector(hv, hv, 2, 3);
      v2h p2 = __builtin_shufflevector(hv, hv, 4, 5);
      v2h p3 = __builtin_shufflevector(hv, hv, 6, 7);
      ar0 = FDOT2(p0, wr[4 * c + 0], ar0); ar1 = FDOT2(p1, wr[4 * c + 1], ar1);
      ar0 = FDOT2(p2, wr[4 * c + 2], ar0); ar1 = FDOT2(p3, wr[4 * c + 3], ar1);
      az0 = FDOT2(p0, wz[4 * c + 0], az0); az1 = FDOT2(p1, wz[4 * c + 1], az1);
      az0 = FDOT2(p2, wz[4 * c + 2], az0); az1 = FDOT2(p3, wz[4 * c + 3], az1);
      an0 = FDOT2(p0, wn[4 * c + 0], an0); an1 = FDOT2(p1, wn[4 * c + 1], an1);
      an0 = FDOT2(p2, wn[4 * c + 2], an0); an1 = FDOT2(p3, wn[4 * c + 3], an1);
    }
    Dr = ar0 + ar1; Dz = az0 + az1; Dn = an0 + an1;
  };

  // ---- encoder: 512 steps, 2 barriers each ----
  for (int t = 0; t < TLEN; ++t) {
    float Dr, Dz, Dn;
    dots(Dr, Dz, Dn);
    pr[tid] = Dr; pz[tid] = Dz; pn[tid] = Dn;
    __syncthreads();                                  // (a) partials visible
    if (tid < HID) {
      float dr = pr[tid] + pr[tid + HID];
      float dz = pz[tid] + pz[tid + HID];
      float dn = pn[tid] + pn[tid + HID];
      float xt = xbuf[t];
      float r  = fast_sigmoid(fmaf(xt, wih_r, bih_r) + dr + bhh_r);
      float z  = fast_sigmoid(fmaf(xt, wih_z, bih_z) + dz + bhh_z);
      float n  = fast_tanh(fmaf(r, dn + bhh_n, fmaf(xt, wih_n, bih_n)));
      float hn = n + z * (hreg - n);
      hreg = hn;
      h16[tid] = (_Float16)hn;
    }
    __syncthreads();                                  // (b) h16 visible
  }

  // ---- switch to decoder weights ----
  LOAD_WEIGHTS(w_hh_dec, w_ih_dec, b_ih_dec, b_hh_dec);

  // seed dense reduction with encoder final h
  if (tid < HID) red[tid] = hreg * wd_reg;
  __syncthreads();

  // ---- decoder: 512 autoregressive steps ----
  for (int t = 0; t < TLEN; ++t) {
    // wave 0: reduce red -> x for THIS step (x0 at t=0; output xs[t-1] for t>0)
    if (tid < 64) {
      float s = (red[tid] + red[tid + 64]) + (red[tid + 128] + red[tid + 192]);
      s += __shfl_down(s, 32);
      s += __shfl_down(s, 16);
      s += __shfl_down(s, 8);
      s += __shfl_down(s, 4);
      s += __shfl_down(s, 2);
      s += __shfl_down(s, 1);
      if (tid == 0) {
        float xn = s + bd;
        xcur_s = xn;
        if (t > 0) obuf[t - 1] = xn;
      }
    }
    float Dr, Dz, Dn;
    dots(Dr, Dz, Dn);
    pr[tid] = Dr; pz[tid] = Dz; pn[tid] = Dn;
    __syncthreads();                                  // (a)
    if (tid < HID) {
      float dr = pr[tid] + pr[tid + HID];
      float dz = pz[tid] + pz[tid + HID];
      float dn = pn[tid] + pn[tid + HID];
      float xt = xcur_s;
      float r  = fast_sigmoid(fmaf(xt, wih_r, bih_r) + dr + bhh_r);
      float z  = fast_sigmoid(fmaf(xt, wih_z, bih_z) + dz + bhh_z);
      float n  = fast_tanh(fmaf(r, dn + bhh_n, fmaf(xt, wih_n, bih_n)));
      float hn = n + z * (hreg - n);
      hreg = hn;
      h16[tid] = (_Float16)hn;
      red[tid] = hn * wd_reg;
    }
    __syncthreads();                                  // (b)
  }

  // final output xs[T-1]
  if (tid < 64) {
    float s = (red[tid] + red[tid + 64]) + (red[tid + 128] + red[tid + 192]);
    s += __shfl_down(s, 32);
    s += __shfl_down(s, 16);
    s += __shfl_down(s, 8);
    s += __shfl_down(s, 4);
    s += __shfl_down(s, 2);
    s += __shfl_down(s, 1);
    if (tid == 0) obuf[TLEN - 1] = s + bd;
  }
  __syncthreads();

  // out[b, t] = xs[T-1-t]  (flip)
  for (int t = tid; t < TLEN; t += NT)
    out[(size_t)b * TLEN + t] = obuf[TLEN - 1 - t];
}

extern "C" void kernel_launch(void* const* d_in, const int* in_sizes, int n_in,
                              void* d_out, int out_size, void* d_ws, size_t ws_size,
                              hipStream_t stream) {
  const float* x        = (const float*)d_in[0];
  const float* w_ih_enc = (const float*)d_in[1];
  const float* w_hh_enc = (const float*)d_in[2];
  const float* b_ih_enc = (const float*)d_in[3];
  const float* b_hh_enc = (const float*)d_in[4];
  const float* w_ih_dec = (const float*)d_in[5];
  const float* w_hh_dec = (const float*)d_in[6];
  const float* b_ih_dec = (const float*)d_in[7];
  const float* b_hh_dec = (const float*)d_in[8];
  const float* w_dense  = (const float*)d_in[9];
  const float* b_dense  = (const float*)d_in[10];
  float* out = (float*)d_out;

  hipLaunchKernelGGL(gru_ae_kernel, dim3(BATCH), dim3(NT), 0, stream,
                     x, w_ih_enc, w_hh_enc, b_ih_enc, b_hh_enc,
                     w_ih_dec, w_hh_dec, b_ih_dec, b_hh_dec,
                     w_dense, b_dense, out);
}